// Round 5
// baseline (298.168 us; speedup 1.0000x reference)
//
#include <hip/hip_runtime.h>
#include <hip/hip_bf16.h>
#include <hip/hip_cooperative_groups.h>
#include <math.h>
#include <stdint.h>

namespace cg = cooperative_groups;

#define B_    2
#define S_    2048
#define HID_  768
#define NH_   12
#define HD_   64
#define NROWS (B_ * S_)                    // 4096
#define N_HID_ELEM (NROWS * HID_)          // 3145728
#define N_W_ELEM   (HID_ * HID_)           // 589824

// attention LDS geometry: 224 staged keys, row stride 232
#define KW   224
#define KSTR 232

// RoPE table: [S][32] float2 (cos, sin)
#define TAB_ELEMS (S_ * 32)

#define GRID_FUSED 384

typedef __bf16 bf16x8 __attribute__((ext_vector_type(8)));
typedef float  floatx4 __attribute__((ext_vector_type(4)));

__device__ __forceinline__ void gload_lds16(const __hip_bfloat16* g, __hip_bfloat16* l)
{
    __builtin_amdgcn_global_load_lds(
        (const __attribute__((address_space(1))) void*)g,
        (__attribute__((address_space(3))) void*)l, 16, 0, 0);
}

__device__ __forceinline__ floatx4 mfma16(bf16x8 a, bf16x8 b, floatx4 c)
{
    return __builtin_amdgcn_mfma_f32_16x16x32_bf16(a, b, c, 0, 0, 0);
}

// ---------------------------------------------------------------------------
// Phase 0: fp32 -> bf16 conversion of hidden + Wq + Wo + RoPE cos/sin table
// ---------------------------------------------------------------------------
__device__ __forceinline__ void convert_body(
    int gtid, int gstride,
    const float* __restrict__ src_hidden, const float* __restrict__ src_w1,
    const float* __restrict__ src_w2, const int* __restrict__ pos_idx,
    __hip_bfloat16* __restrict__ Hb, __hip_bfloat16* __restrict__ Wqb,
    __hip_bfloat16* __restrict__ Wob, float2* __restrict__ tab)
{
    const int NH4 = N_HID_ELEM / 4, NW4 = N_W_ELEM / 4;
    const int total4 = NH4 + 2 * NW4;
    const int total  = total4 + TAB_ELEMS;
    for (int i = gtid; i < total; i += gstride) {
        if (i < total4) {
            const float* src;
            __hip_bfloat16* dst;
            int off;
            if (i < NH4)           { src = src_hidden; dst = Hb;  off = i; }
            else if (i < NH4+NW4)  { src = src_w1;     dst = Wqb; off = i - NH4; }
            else                   { src = src_w2;     dst = Wob; off = i - NH4 - NW4; }
            float4 v = reinterpret_cast<const float4*>(src)[off];
            __hip_bfloat16 o[4] = { __float2bfloat16(v.x), __float2bfloat16(v.y),
                                    __float2bfloat16(v.z), __float2bfloat16(v.w) };
            *reinterpret_cast<uint64_t*>(dst + 4 * (size_t)off) =
                *reinterpret_cast<uint64_t*>(o);
        } else {
            int t = i - total4;
            int s = t >> 5, f = t & 31;
            float inv = exp2f((float)f * (-0.41524101186092024f)); // -log2(1e4)/32
            float sn, cs;
            sincosf((float)pos_idx[s] * inv, &sn, &cs);
            tab[t] = make_float2(cs, sn);
        }
    }
}

// ---------------------------------------------------------------------------
// 128x64-tile GEMM, 256 threads (4 waves), NO split-K: C = A @ W^T, K=768.
// Wave wv owns rows [wv*32, wv*32+32) x all 64 cols -> acc[2][4] 16x16 frags.
// 12 K-steps of BK=64; glds staging, depth-2 prefetch, counted vmcnt(6)
// (6 glds/wave/stage). Per K-step: 16 MFMA : 12 ds_read_b128 (vs 8:10 in the
// old split-K 64^2) and no cross-group reduction.
// LDS linear [buf][row][64]; 16B granule swizzle g_phys = g_log ^ (row&7)
// applied on the GLOBAL source (glds dest must be linear, rule #21) and on
// the read -> row-component = 0 mod 32 banks, granule perm spreads the 16
// lanes of each quad over all 8 bank-groups = 2 lanes/group = free.
// ---------------------------------------------------------------------------
template<int ROPE>
__device__ __forceinline__ void gemm_tile(
    const __hip_bfloat16* __restrict__ A,
    const __hip_bfloat16* __restrict__ W,
    __hip_bfloat16* __restrict__ C,        // ROPE: Q
    __hip_bfloat16* __restrict__ C2,       // ROPE: Qr
    float* __restrict__ Cf,                // !ROPE
    const float2* __restrict__ tab,
    char* smem, int m0, int n0)
{
    constexpr int K = HID_;
    auto Ald = reinterpret_cast<__hip_bfloat16(*)[128][64]>(smem);          // 32 KB
    auto Wld = reinterpret_cast<__hip_bfloat16(*)[64][64]>(smem + 32768);   // 16 KB

    const int tid  = threadIdx.x;
    const int wv   = tid >> 6;
    const int lane = tid & 63;
    const int l16  = lane & 15;
    const int quad = lane >> 4;

    // staging: A = 1024 chunks/iter (4 glds/thread), W = 512 (2 glds/thread)
    // chunk = k*256 + wv*64 + lane; row = chunk>>3; s_phys = chunk&7;
    // source granule = s_phys ^ (row&7)  (inverse of the read swizzle)
    const int ch0 = wv * 64 + lane;
    const __hip_bfloat16 *gA0, *gA1, *gA2, *gA3, *gW0, *gW1;
    {
        int ch, row, sp;
        ch = ch0;        row = ch >> 3; sp = ch & 7;
        gA0 = A + (size_t)(m0 + row) * K + ((sp ^ (row & 7)) << 3);
        ch = 256 + ch0;  row = ch >> 3; sp = ch & 7;
        gA1 = A + (size_t)(m0 + row) * K + ((sp ^ (row & 7)) << 3);
        ch = 512 + ch0;  row = ch >> 3; sp = ch & 7;
        gA2 = A + (size_t)(m0 + row) * K + ((sp ^ (row & 7)) << 3);
        ch = 768 + ch0;  row = ch >> 3; sp = ch & 7;
        gA3 = A + (size_t)(m0 + row) * K + ((sp ^ (row & 7)) << 3);
        ch = ch0;        row = ch >> 3; sp = ch & 7;
        gW0 = W + (size_t)(n0 + row) * K + ((sp ^ (row & 7)) << 3);
        ch = 256 + ch0;  row = ch >> 3; sp = ch & 7;
        gW1 = W + (size_t)(n0 + row) * K + ((sp ^ (row & 7)) << 3);
    }

    floatx4 acc[2][4] = {};

    auto STG = [&](int itx, int buf) {
        const int ko = itx * 64;
        __hip_bfloat16* ab = &Ald[buf][0][0] + wv * 512;   // (wv*64)*8 elems
        __hip_bfloat16* wb = &Wld[buf][0][0] + wv * 512;
        gload_lds16(gA0 + ko, ab);
        gload_lds16(gA1 + ko, ab + 2048);
        gload_lds16(gA2 + ko, ab + 4096);
        gload_lds16(gA3 + ko, ab + 6144);
        gload_lds16(gW0 + ko, wb);
        gload_lds16(gW1 + ko, wb + 2048);
    };

    STG(0, 0);
    STG(1, 1);

#pragma unroll
    for (int it = 0; it < 12; ++it) {
        const int cur = it & 1;
        if (it == 11) { asm volatile("s_waitcnt vmcnt(0)" ::: "memory"); }
        else          { asm volatile("s_waitcnt vmcnt(6)" ::: "memory"); }
        __builtin_amdgcn_s_barrier();          // all waves' stage(it) landed
        __builtin_amdgcn_sched_barrier(0);     // no ds_read hoists above this
#pragma unroll
        for (int ks = 0; ks < 2; ++ks) {
            const int gsw = ((ks * 4 + quad) ^ (l16 & 7)) * 8;
            bf16x8 a0 = *reinterpret_cast<const bf16x8*>(&Ald[cur][wv * 32 + l16][gsw]);
            bf16x8 a1 = *reinterpret_cast<const bf16x8*>(&Ald[cur][wv * 32 + 16 + l16][gsw]);
#pragma unroll
            for (int u = 0; u < 4; ++u) {
                bf16x8 w = *reinterpret_cast<const bf16x8*>(&Wld[cur][u * 16 + l16][gsw]);
                acc[0][u] = mfma16(a0, w, acc[0][u]);
                acc[1][u] = mfma16(a1, w, acc[1][u]);
            }
        }
        __builtin_amdgcn_sched_barrier(0);     // no ds_read sinks below this
        __builtin_amdgcn_s_barrier();          // all reads of buf 'cur' retired
        if (it + 2 < 12) STG(it + 2, cur);     // overwrite just-freed buffer
    }

    // ---- epilogue: D row = m0 + wv*32 + f*16 + quad*4 + r, col = n0+u*16+l16
    if (ROPE) {
#pragma unroll
        for (int f = 0; f < 2; ++f)
#pragma unroll
        for (int r = 0; r < 4; ++r) {
            int m = m0 + wv * 32 + f * 16 + quad * 4 + r;
            int s = m & (S_ - 1);
#pragma unroll
            for (int u = 0; u < 2; ++u) {
                float2 cssn = tab[s * 32 + u * 16 + l16];
                float cs = cssn.x, sn = cssn.y;
                float q0 = acc[f][u][r];
                float q1 = acc[f][u + 2][r];
                size_t base = (size_t)m * HID_ + n0 + u * 16 + l16;
                C [base]      = __float2bfloat16(q0);
                C [base + 32] = __float2bfloat16(q1);
                C2[base]      = __float2bfloat16(q0 * cs - q1 * sn);
                C2[base + 32] = __float2bfloat16(q1 * cs + q0 * sn);
            }
        }
    } else {
#pragma unroll
        for (int f = 0; f < 2; ++f)
#pragma unroll
        for (int u = 0; u < 4; ++u)
#pragma unroll
            for (int r = 0; r < 4; ++r) {
                int row = m0 + wv * 32 + f * 16 + quad * 4 + r;
                int col = n0 + u * 16 + l16;
                Cf[(size_t)row * HID_ + col] = acc[f][u][r];
            }
    }
}

// ---------------------------------------------------------------------------
// Banded attention tile (R4-proven body): K^T staged via glds (pre-swizzled
// source), Kr union'd with Pl, conflict-free Vt staging, setprio on MFMA.
// ---------------------------------------------------------------------------
__device__ __forceinline__ void attn_tile(
    const __hip_bfloat16* __restrict__ Q,    // pre-rope  (= V)
    const __hip_bfloat16* __restrict__ Qr,   // post-rope (= Q = K)
    __hip_bfloat16* __restrict__ O,
    char* smem, int b, int h, int i0)
{
    auto Vt = reinterpret_cast<__hip_bfloat16(*)[KSTR]>(smem);            // 29 KB
    __hip_bfloat16* KP = reinterpret_cast<__hip_bfloat16*>(smem + 64 * KSTR * 2); // 29 KB

    const int tid = threadIdx.x;

    // ---- stage V^T: one key row per lane (banks = tid/2 -> 2-way = free) ----
    if (tid < KW) {
        int j  = i0 - 64 + tid;
        int jc = min(max(j, 0), S_ - 1);
        const __hip_bfloat16* vrow = Q + ((size_t)(b * S_ + jc)) * HID_ + h * HD_;
#pragma unroll
        for (int d8i = 0; d8i < 8; ++d8i) {
            bf16x8 v = *reinterpret_cast<const bf16x8*>(vrow + d8i * 8);
            const __hip_bfloat16* ve = reinterpret_cast<const __hip_bfloat16*>(&v);
#pragma unroll
            for (int e = 0; e < 8; ++e) Vt[d8i * 8 + e][tid] = ve[e];
        }
    }

    // ---- stage Kr (224x64 bf16 = 28 KB) via glds, source pre-swizzled ----
    {
        const int wvb = (tid >> 6) * 64;
        const int ln  = tid & 63;
#pragma unroll
        for (int i = 0; i < 7; ++i) {
            int cbase = i * 256 + wvb;
            int cc  = cbase + ln;
            int row = cc >> 3;
            int gp  = cc & 7;
            int gl  = gp ^ (row & 7);
            int j   = i0 - 64 + row;
            int jc  = min(max(j, 0), S_ - 1);
            gload_lds16(Qr + ((size_t)(b * S_ + jc)) * HID_ + h * HD_ + gl * 8,
                        KP + (size_t)cbase * 8);
        }
    }
    __syncthreads();

    const int wv   = tid >> 6;
    const int lane = tid & 63;
    const int l16  = lane & 15;
    const int quad = lane >> 4;

    // ---- QK^T over the 10 tiles intersecting this wave's band ----
    floatx4 sc[10] = {};
    const __hip_bfloat16* qrow =
        Qr + ((size_t)(b * S_ + i0 + wv * 16 + l16)) * HID_ + h * HD_ + quad * 8;
    __builtin_amdgcn_s_setprio(1);
#pragma unroll
    for (int ks = 0; ks < 2; ++ks) {
        bf16x8 a = *reinterpret_cast<const bf16x8*>(qrow + ks * 32);
#pragma unroll
        for (int t = 0; t < 10; ++t) {
            int w  = (wv + t) * 16 + l16;
            int gp = ((ks * 4 + quad) ^ (w & 7)) * 8;
            bf16x8 bfr = *reinterpret_cast<const bf16x8*>(&KP[w * 64 + gp]);
            sc[t] = mfma16(a, bfr, sc[t]);
        }
    }
    __builtin_amdgcn_s_setprio(0);
    __syncthreads();                       // all Kr reads done; KP becomes Pl

    // ---- masked softmax per row ----
    const float scale = 0.125f;
    float denom[4];
#pragma unroll
    for (int r = 0; r < 4; ++r) {
        const int R = wv * 16 + quad * 4 + r;
        float xv[10];
        float mx = -3.0e38f;
#pragma unroll
        for (int t = 0; t < 10; ++t) {
            int w = (wv + t) * 16 + l16;
            int j = i0 - 64 + w;
            bool valid = (w >= R) && (w <= R + 128) && (j >= 0) && (j < S_);
            float x = valid ? sc[t][r] * scale : -1.0e30f;
            xv[t] = x;
            mx = fmaxf(mx, x);
        }
#pragma unroll
        for (int msk = 1; msk < 16; msk <<= 1) mx = fmaxf(mx, __shfl_xor(mx, msk, 64));
        float sum = 0.f;
#pragma unroll
        for (int t = 0; t < 10; ++t) {
            float p = __expf(xv[t] - mx);
            sum += p;
            KP[R * KSTR + (wv + t) * 16 + l16] = __float2bfloat16(p);
        }
#pragma unroll
        for (int msk = 1; msk < 16; msk <<= 1) sum += __shfl_xor(sum, msk, 64);
        denom[r] = sum;
    }
    __syncthreads();

    // ---- PV over the wave's 160-wide band ----
    floatx4 oacc[4] = {};
    __builtin_amdgcn_s_setprio(1);
#pragma unroll
    for (int c = 0; c < 5; ++c) {
        const int base = wv * 16 + c * 32;
        bf16x8 a = *reinterpret_cast<const bf16x8*>(
            &KP[(wv * 16 + l16) * KSTR + base + quad * 8]);
#pragma unroll
        for (int u = 0; u < 4; ++u) {
            bf16x8 bfr = *reinterpret_cast<const bf16x8*>(&Vt[u * 16 + l16][base + quad * 8]);
            oacc[u] = mfma16(a, bfr, oacc[u]);
        }
    }
    __builtin_amdgcn_s_setprio(0);

    // ---- O writeback via LDS repack (reuse KP as f32 [64][68]) ----
    __syncthreads();
    float* Of = reinterpret_cast<float*>(KP);
#pragma unroll
    for (int u = 0; u < 4; ++u)
#pragma unroll
        for (int r = 0; r < 4; ++r)
            Of[(wv * 16 + quad * 4 + r) * 68 + u * 16 + l16] = oacc[u][r] / denom[r];
    __syncthreads();
    {
        int row = tid >> 2;
        int seg = (tid & 3) * 16;
        __hip_bfloat16 ob[16];
#pragma unroll
        for (int e = 0; e < 16; ++e)
            ob[e] = __float2bfloat16(Of[row * 68 + seg + e]);
        __hip_bfloat16* dst = O + ((size_t)(b * S_ + i0 + row)) * HID_ + h * HD_ + seg;
        *reinterpret_cast<bf16x8*>(dst)     = *reinterpret_cast<bf16x8*>(ob);
        *reinterpret_cast<bf16x8*>(dst + 8) = *reinterpret_cast<bf16x8*>(ob + 8);
    }
}

// ---------------------------------------------------------------------------
// Fused cooperative kernel: convert -> gemm1+rope -> attn x2 -> gemm2.
// 384 blocks x 256 threads, 58 KB LDS, __launch_bounds__(256,2) -> 2 blk/CU,
// 384 <= 512 co-resident slots (cooperative launch validates).
// ---------------------------------------------------------------------------
__global__ __launch_bounds__(256, 2) void fused_kernel(
    const float* __restrict__ hidden, const float* __restrict__ w1,
    const float* __restrict__ w2, const int* __restrict__ pos,
    __hip_bfloat16* __restrict__ Hb, __hip_bfloat16* __restrict__ Wqb,
    __hip_bfloat16* __restrict__ Wob, __hip_bfloat16* __restrict__ Q,
    __hip_bfloat16* __restrict__ Qr, float2* __restrict__ Tab,
    __hip_bfloat16* __restrict__ AO, float* __restrict__ out)
{
    __shared__ __align__(16) char smem[59392];
    cg::grid_group grid = cg::this_grid();

    // P0: convert + rope table
    convert_body(blockIdx.x * 256 + threadIdx.x, GRID_FUSED * 256,
                 hidden, w1, w2, pos, Hb, Wqb, Wob, Tab);
    grid.sync();

    // P1: gemm1 + rope -> Q, Qr   (384 tiles of 128x64, one perfect round)
    {
        const int t = blockIdx.x;
        gemm_tile<1>(Hb, Wqb, Q, Qr, nullptr, Tab, smem,
                     (t & 31) * 128, (t >> 5) * 64);
    }
    grid.sync();

    // P2: attention, 768 tiles, 2 per block (balanced)
#pragma unroll
    for (int k = 0; k < 2; ++k) {
        __syncthreads();                    // smem reuse guard between tiles
        const int tt = blockIdx.x + k * GRID_FUSED;
        const int i0 = (tt & 31) * 64;
        const int bh = tt >> 5;
        attn_tile(Q, Qr, AO, smem, bh / NH_, bh % NH_, i0);
    }
    grid.sync();

    // P3: gemm2 -> fp32 out
    {
        const int t = blockIdx.x;
        gemm_tile<0>(AO, Wob, nullptr, nullptr, out, nullptr, smem,
                     (t & 31) * 128, (t >> 5) * 64);
    }
}

// ---------------------------------------------------------------------------
// Non-cooperative fallback (same device functions, 4 launches)
// ---------------------------------------------------------------------------
__global__ void convert_fb(const float* __restrict__ h, const float* __restrict__ w1,
                           const float* __restrict__ w2, const int* __restrict__ pos,
                           __hip_bfloat16* __restrict__ Hb, __hip_bfloat16* __restrict__ Wqb,
                           __hip_bfloat16* __restrict__ Wob, float2* __restrict__ tab)
{
    convert_body(blockIdx.x * blockDim.x + threadIdx.x, gridDim.x * blockDim.x,
                 h, w1, w2, pos, Hb, Wqb, Wob, tab);
}

__global__ __launch_bounds__(256) void gemm1_fb(
    const __hip_bfloat16* __restrict__ A, const __hip_bfloat16* __restrict__ W,
    __hip_bfloat16* __restrict__ C, __hip_bfloat16* __restrict__ C2,
    const float2* __restrict__ tab)
{
    __shared__ __align__(16) char smem[49152];
    const int t = blockIdx.x;
    gemm_tile<1>(A, W, C, C2, nullptr, tab, smem, (t & 31) * 128, (t >> 5) * 64);
}

__global__ __launch_bounds__(256) void gemm2_fb(
    const __hip_bfloat16* __restrict__ A, const __hip_bfloat16* __restrict__ W,
    float* __restrict__ out)
{
    __shared__ __align__(16) char smem[49152];
    const int t = blockIdx.x;
    gemm_tile<0>(A, W, nullptr, nullptr, out, nullptr, smem, (t & 31) * 128, (t >> 5) * 64);
}

__global__ __launch_bounds__(256) void attn_fb(
    const __hip_bfloat16* __restrict__ Q, const __hip_bfloat16* __restrict__ Qr,
    __hip_bfloat16* __restrict__ O)
{
    __shared__ __align__(16) char smem[59392];
    attn_tile(Q, Qr, O, smem, blockIdx.y / NH_, blockIdx.y % NH_, blockIdx.x * 64);
}

// ---------------------------------------------------------------------------
extern "C" void kernel_launch(void* const* d_in, const int* in_sizes, int n_in,
                              void* d_out, int out_size, void* d_ws, size_t ws_size,
                              hipStream_t stream)
{
    int ih = -1, iw1 = -1, iw2 = -1, ip = -1;
    for (int i = 0; i < n_in; ++i) {
        int s = in_sizes[i];
        if      (s == N_HID_ELEM && ih < 0) ih = i;
        else if (s == N_W_ELEM)  { if (iw1 < 0) iw1 = i; else if (iw2 < 0) iw2 = i; }
        else if (s == S_ && ip < 0) ip = i;
    }
    if (ih < 0)  ih = 0;
    if (iw1 < 0) iw1 = 1;
    if (iw2 < 0) iw2 = 2;
    if (ip < 0)  ip = 5;

    const float* hidden = (const float*)d_in[ih];
    const float* w1     = (const float*)d_in[iw1];   // Wq
    const float* w2     = (const float*)d_in[iw2];   // Wo
    const int*   pos    = (const int*)d_in[ip];

    __hip_bfloat16* Hb  = (__hip_bfloat16*)d_ws;
    __hip_bfloat16* Wqb = Hb  + N_HID_ELEM;
    __hip_bfloat16* Wob = Wqb + N_W_ELEM;
    __hip_bfloat16* Q   = Wob + N_W_ELEM;
    __hip_bfloat16* Qr  = Q   + N_HID_ELEM;
    float2*         Tab = reinterpret_cast<float2*>(Qr + N_HID_ELEM);  // 512 KB
    __hip_bfloat16* AO  = Hb;   // Hb dead after gemm1 phase
    float*          outp = (float*)d_out;

    void* args[12] = { (void*)&hidden, (void*)&w1, (void*)&w2, (void*)&pos,
                       (void*)&Hb, (void*)&Wqb, (void*)&Wob, (void*)&Q,
                       (void*)&Qr, (void*)&Tab, (void*)&AO, (void*)&outp };

    hipError_t e = hipLaunchCooperativeKernel((const void*)fused_kernel,
                                              dim3(GRID_FUSED), dim3(256),
                                              args, 0, stream);
    if (e != hipSuccess) {
        // fallback: identical math via 4 plain launches
        int conv4 = (N_HID_ELEM + 2 * N_W_ELEM) / 4 + TAB_ELEMS;
        convert_fb<<<(conv4 + 255) / 256, 256, 0, stream>>>(
            hidden, w1, w2, pos, Hb, Wqb, Wob, Tab);
        gemm1_fb<<<GRID_FUSED, 256, 0, stream>>>(Hb, Wqb, Q, Qr, Tab);
        attn_fb<<<dim3(S_ / 64, B_ * NH_), 256, 0, stream>>>(Q, Qr, AO);
        gemm2_fb<<<GRID_FUSED, 256, 0, stream>>>(AO, Wob, outp);
    }
}

// Round 6
// 136.589 us; speedup vs baseline: 2.1830x; 2.1830x over previous
//
#include <hip/hip_runtime.h>
#include <hip/hip_bf16.h>
#include <math.h>
#include <stdint.h>

#define B_    2
#define S_    2048
#define HID_  768
#define NH_   12
#define HD_   64
#define NROWS (B_ * S_)                    // 4096
#define N_HID_ELEM (NROWS * HID_)          // 3145728
#define N_W_ELEM   (HID_ * HID_)           // 589824

// attention LDS geometry: 224 staged keys, row stride 232
#define KW   224
#define KSTR 232

// RoPE table: [S][32] float2 (cos, sin)
#define TAB_ELEMS (S_ * 32)

typedef __bf16 bf16x8 __attribute__((ext_vector_type(8)));
typedef float  floatx4 __attribute__((ext_vector_type(4)));

// fp32 -> bf16 conversion of hidden + Wq + Wo (x4 vectorized) + RoPE cos/sin table
__global__ void convert_inputs_kernel(const float* __restrict__ src_hidden,
                                      const float* __restrict__ src_w1,
                                      const float* __restrict__ src_w2,
                                      const int*   __restrict__ pos_idx,
                                      __hip_bfloat16* __restrict__ Hb,
                                      __hip_bfloat16* __restrict__ Wqb,
                                      __hip_bfloat16* __restrict__ Wob,
                                      float2* __restrict__ tab)
{
    int i = blockIdx.x * blockDim.x + threadIdx.x;   // float4 index
    const int NH4 = N_HID_ELEM / 4, NW4 = N_W_ELEM / 4;
    const int total4 = NH4 + 2 * NW4;
    if (i < total4) {
        const float* src;
        __hip_bfloat16* dst;
        int off;
        if (i < NH4)           { src = src_hidden; dst = Hb;  off = i; }
        else if (i < NH4+NW4)  { src = src_w1;     dst = Wqb; off = i - NH4; }
        else                   { src = src_w2;     dst = Wob; off = i - NH4 - NW4; }
        float4 v = reinterpret_cast<const float4*>(src)[off];
        __hip_bfloat16 o[4] = { __float2bfloat16(v.x), __float2bfloat16(v.y),
                                __float2bfloat16(v.z), __float2bfloat16(v.w) };
        *reinterpret_cast<uint64_t*>(dst + 4 * (size_t)off) = *reinterpret_cast<uint64_t*>(o);
    } else {
        int t = i - total4;
        if (t < TAB_ELEMS) {
            int s = t >> 5, f = t & 31;
            float inv = exp2f((float)f * (-0.41524101186092024f)); // -log2(1e4)/32
            float sn, cs;
            sincosf((float)pos_idx[s] * inv, &sn, &cs);
            tab[t] = make_float2(cs, sn);
        }
    }
}

__device__ __forceinline__ void gload_lds16(const __hip_bfloat16* g, __hip_bfloat16* l)
{
    __builtin_amdgcn_global_load_lds(
        (const __attribute__((address_space(1))) void*)g,
        (__attribute__((address_space(3))) void*)l, 16, 0, 0);
}

// ---------------------------------------------------------------------------
// 64x64-tile GEMM, 256 threads (4 waves), NO split-K: C = A @ W^T, K=768.
// Occupancy-targeted restructure of the R4-proven kernel: per-wave read
// geometry, staging map, XOR swizzle, and epilogue are bit-identical to R4's
// per-kg versions; only the kg dimension is removed (K-loop 12 iters) and
// the cross-group reduction is gone.  LDS 32 KB + __launch_bounds__(256,5)
// -> 5 blocks/CU = 20 waves/CU (vs R4's 16), and all 768 blocks co-resident
// in a single scheduling round (768 <= 5*256) -- no half-empty tail round.
// glds staging, depth-2 prefetch, counted vmcnt(4) (4 glds/thread/stage).
// ---------------------------------------------------------------------------
template<int ROPE>
__global__ __launch_bounds__(256, 5) void gemm64ns(
    const __hip_bfloat16* __restrict__ A,
    const __hip_bfloat16* __restrict__ W,
    __hip_bfloat16* __restrict__ C,        // ROPE: Q
    __hip_bfloat16* __restrict__ C2,       // ROPE: Qr
    float* __restrict__ Cf,                // !ROPE
    const float2* __restrict__ tab,
    int M, int N, int K)
{
    // [buf][half][row][32]  (row stride 64B; LDS kept LINEAR for glds)
    __shared__ __align__(16) __hip_bfloat16 Ald[2][2][64][32];  // 16 KB
    __shared__ __align__(16) __hip_bfloat16 Wld[2][2][64][32];  // 16 KB

    const int tid  = threadIdx.x;
    const int wv   = tid >> 6;             // wave 0..3
    const int lane = tid & 63;
    const int l16  = lane & 15;
    const int quad = lane >> 4;
    const int m0 = blockIdx.x * 64;
    const int n0 = blockIdx.y * 64;

    // staging geometry: chunk c in [0,256): row=c>>2, slot=c&3.
    // Physical slot receives logical k-granule  slot ^ ((row>>1)&3).
    const int c    = wv * 64 + lane;
    const int sr   = c >> 2;
    const int sc8  = ((c & 3) ^ ((sr >> 1) & 3)) * 8;   // pre-swizzled global k-offset

    const __hip_bfloat16* gA = A + (size_t)(m0 + sr) * K + sc8;
    const __hip_bfloat16* gW = W + (size_t)(n0 + sr) * K + sc8;

    floatx4 acc[4] = {};
    const int ra  = wv * 16 + l16;                       // A-fragment row for this lane
    const int qsw = (quad ^ ((l16 >> 1) & 3)) * 8;       // swizzled read granule (elems)

#define STAGE(itx, buf) do {                                      \
        const int ko_ = (itx) * 64;                               \
        gload_lds16(gA + ko_,      &Ald[buf][0][wv * 16][0]);     \
        gload_lds16(gA + ko_ + 32, &Ald[buf][1][wv * 16][0]);     \
        gload_lds16(gW + ko_,      &Wld[buf][0][wv * 16][0]);     \
        gload_lds16(gW + ko_ + 32, &Wld[buf][1][wv * 16][0]);     \
    } while (0)

    // prologue: two tiles in flight
    STAGE(0, 0);
    STAGE(1, 1);

#pragma unroll
    for (int it = 0; it < 12; ++it) {
        const int cur = it & 1;
        if (it == 11) { asm volatile("s_waitcnt vmcnt(0)" ::: "memory"); }
        else          { asm volatile("s_waitcnt vmcnt(4)" ::: "memory"); }
        __builtin_amdgcn_s_barrier();          // all waves' stage(it) landed
        __builtin_amdgcn_sched_barrier(0);     // no ds_read hoists above this
#pragma unroll
        for (int ks = 0; ks < 2; ++ks) {
            bf16x8 a = *reinterpret_cast<const bf16x8*>(&Ald[cur][ks][ra][qsw]);
#pragma unroll
            for (int u = 0; u < 4; ++u) {
                bf16x8 w = *reinterpret_cast<const bf16x8*>(
                    &Wld[cur][ks][u * 16 + l16][qsw]);
                acc[u] = __builtin_amdgcn_mfma_f32_16x16x32_bf16(a, w, acc[u], 0, 0, 0);
            }
        }
        __builtin_amdgcn_sched_barrier(0);     // no ds_read sinks below this
        __builtin_amdgcn_s_barrier();          // all reads of buf 'cur' retired
        if (it + 2 < 12) STAGE(it + 2, cur);   // overwrite just-freed buffer
    }
#undef STAGE

    // ---- epilogue: D row = m0 + wv*16 + quad*4 + r, col = n0 + u*16 + l16 ----
    if (ROPE) {
#pragma unroll
        for (int r = 0; r < 4; ++r) {
            int m = m0 + wv * 16 + quad * 4 + r;
            int s = m & (S_ - 1);
#pragma unroll
            for (int u = 0; u < 2; ++u) {
                float2 cssn = tab[s * 32 + u * 16 + l16];
                float cs = cssn.x, sn = cssn.y;
                float q0 = acc[u][r];
                float q1 = acc[u + 2][r];
                size_t base = (size_t)m * HID_ + n0 + u * 16 + l16;
                C [base]      = __float2bfloat16(q0);
                C [base + 32] = __float2bfloat16(q1);
                C2[base]      = __float2bfloat16(q0 * cs - q1 * sn);
                C2[base + 32] = __float2bfloat16(q1 * cs + q0 * sn);
            }
        }
    } else {
#pragma unroll
        for (int u = 0; u < 4; ++u)
#pragma unroll
            for (int r = 0; r < 4; ++r) {
                int row = m0 + wv * 16 + quad * 4 + r;
                int col = n0 + u * 16 + l16;
                Cf[(size_t)row * N + col] = acc[u][r];
            }
    }
}

// ---------------------------------------------------------------------------
// Banded attention (R4-proven): K^T staged via glds (pre-swizzled source),
// Kr union'd with Pl, conflict-free Vt staging, setprio on MFMA clusters.
// ---------------------------------------------------------------------------
__global__ __launch_bounds__(256) void attn_kernel(
    const __hip_bfloat16* __restrict__ Q,    // pre-rope  (= V)
    const __hip_bfloat16* __restrict__ Qr,   // post-rope (= Q = K)
    __hip_bfloat16* __restrict__ O)
{
    __shared__ __align__(16) __hip_bfloat16 Vt[64][KSTR];   // [dim][window]  29 KB
    __shared__ __align__(16) __hip_bfloat16 KP[64 * KSTR];  // Kr then Pl     29 KB

    const int bh = blockIdx.y;
    const int b  = bh / NH_;
    const int h  = bh % NH_;
    const int i0 = blockIdx.x * 64;
    const int tid = threadIdx.x;

    // ---- stage V^T: one key row per lane (banks = tid/2 -> 2-way = free) ----
    if (tid < KW) {
        int j  = i0 - 64 + tid;
        int jc = min(max(j, 0), S_ - 1);
        const __hip_bfloat16* vrow = Q + ((size_t)(b * S_ + jc)) * HID_ + h * HD_;
#pragma unroll
        for (int d8i = 0; d8i < 8; ++d8i) {
            bf16x8 v = *reinterpret_cast<const bf16x8*>(vrow + d8i * 8);
            const __hip_bfloat16* ve = reinterpret_cast<const __hip_bfloat16*>(&v);
#pragma unroll
            for (int e = 0; e < 8; ++e) Vt[d8i * 8 + e][tid] = ve[e];
        }
    }

    // ---- stage Kr (224x64 bf16 = 28 KB) via glds, source pre-swizzled ----
    {
        const int wvb = (tid >> 6) * 64;
        const int ln  = tid & 63;
#pragma unroll
        for (int i = 0; i < 7; ++i) {
            int cbase = i * 256 + wvb;
            int cc  = cbase + ln;
            int row = cc >> 3;
            int gp  = cc & 7;
            int gl  = gp ^ (row & 7);
            int j   = i0 - 64 + row;
            int jc  = min(max(j, 0), S_ - 1);
            gload_lds16(Qr + ((size_t)(b * S_ + jc)) * HID_ + h * HD_ + gl * 8,
                        KP + (size_t)cbase * 8);
        }
    }
    __syncthreads();

    const int wv   = tid >> 6;
    const int lane = tid & 63;
    const int l16  = lane & 15;
    const int quad = lane >> 4;

    // ---- QK^T over the 10 tiles intersecting this wave's band ----
    floatx4 sc[10] = {};
    const __hip_bfloat16* qrow =
        Qr + ((size_t)(b * S_ + i0 + wv * 16 + l16)) * HID_ + h * HD_ + quad * 8;
    __builtin_amdgcn_s_setprio(1);
#pragma unroll
    for (int ks = 0; ks < 2; ++ks) {
        bf16x8 a = *reinterpret_cast<const bf16x8*>(qrow + ks * 32);
#pragma unroll
        for (int t = 0; t < 10; ++t) {
            int w  = (wv + t) * 16 + l16;
            int gp = ((ks * 4 + quad) ^ (w & 7)) * 8;
            bf16x8 bfr = *reinterpret_cast<const bf16x8*>(&KP[w * 64 + gp]);
            sc[t] = __builtin_amdgcn_mfma_f32_16x16x32_bf16(a, bfr, sc[t], 0, 0, 0);
        }
    }
    __builtin_amdgcn_s_setprio(0);
    __syncthreads();                       // all Kr reads done; KP becomes Pl

    // ---- masked softmax per row ----
    const float scale = 0.125f;
    float denom[4];
#pragma unroll
    for (int r = 0; r < 4; ++r) {
        const int R = wv * 16 + quad * 4 + r;
        float xv[10];
        float mx = -3.0e38f;
#pragma unroll
        for (int t = 0; t < 10; ++t) {
            int w = (wv + t) * 16 + l16;
            int j = i0 - 64 + w;
            bool valid = (w >= R) && (w <= R + 128) && (j >= 0) && (j < S_);
            float x = valid ? sc[t][r] * scale : -1.0e30f;
            xv[t] = x;
            mx = fmaxf(mx, x);
        }
#pragma unroll
        for (int msk = 1; msk < 16; msk <<= 1) mx = fmaxf(mx, __shfl_xor(mx, msk, 64));
        float sum = 0.f;
#pragma unroll
        for (int t = 0; t < 10; ++t) {
            float p = __expf(xv[t] - mx);
            sum += p;
            KP[R * KSTR + (wv + t) * 16 + l16] = __float2bfloat16(p);
        }
#pragma unroll
        for (int msk = 1; msk < 16; msk <<= 1) sum += __shfl_xor(sum, msk, 64);
        denom[r] = sum;
    }
    __syncthreads();

    // ---- PV over the wave's 160-wide band ----
    floatx4 oacc[4] = {};
    __builtin_amdgcn_s_setprio(1);
#pragma unroll
    for (int c = 0; c < 5; ++c) {
        const int base = wv * 16 + c * 32;
        bf16x8 a = *reinterpret_cast<const bf16x8*>(
            &KP[(wv * 16 + l16) * KSTR + base + quad * 8]);
#pragma unroll
        for (int u = 0; u < 4; ++u) {
            bf16x8 bfr = *reinterpret_cast<const bf16x8*>(&Vt[u * 16 + l16][base + quad * 8]);
            oacc[u] = __builtin_amdgcn_mfma_f32_16x16x32_bf16(a, bfr, oacc[u], 0, 0, 0);
        }
    }
    __builtin_amdgcn_s_setprio(0);

    // ---- O writeback via LDS repack (reuse KP as f32 [64][68]) ----
    __syncthreads();                       // all Pl/Vt reads done
    float* Of = reinterpret_cast<float*>(&KP[0]);
#pragma unroll
    for (int u = 0; u < 4; ++u)
#pragma unroll
        for (int r = 0; r < 4; ++r)
            Of[(wv * 16 + quad * 4 + r) * 68 + u * 16 + l16] = oacc[u][r] / denom[r];
    __syncthreads();
    {
        int row = tid >> 2;
        int seg = (tid & 3) * 16;
        __hip_bfloat16 ob[16];
#pragma unroll
        for (int e = 0; e < 16; ++e)
            ob[e] = __float2bfloat16(Of[row * 68 + seg + e]);
        __hip_bfloat16* dst = O + ((size_t)(b * S_ + i0 + row)) * HID_ + h * HD_ + seg;
        *reinterpret_cast<bf16x8*>(dst)     = *reinterpret_cast<bf16x8*>(ob);
        *reinterpret_cast<bf16x8*>(dst + 8) = *reinterpret_cast<bf16x8*>(ob + 8);
    }
}

// ---------------------------------------------------------------------------
extern "C" void kernel_launch(void* const* d_in, const int* in_sizes, int n_in,
                              void* d_out, int out_size, void* d_ws, size_t ws_size,
                              hipStream_t stream)
{
    int ih = -1, iw1 = -1, iw2 = -1, ip = -1;
    for (int i = 0; i < n_in; ++i) {
        int s = in_sizes[i];
        if      (s == N_HID_ELEM && ih < 0) ih = i;
        else if (s == N_W_ELEM)  { if (iw1 < 0) iw1 = i; else if (iw2 < 0) iw2 = i; }
        else if (s == S_ && ip < 0) ip = i;
    }
    if (ih < 0)  ih = 0;
    if (iw1 < 0) iw1 = 1;
    if (iw2 < 0) iw2 = 2;
    if (ip < 0)  ip = 5;

    const float* hidden = (const float*)d_in[ih];
    const float* w1     = (const float*)d_in[iw1];
    const float* w2     = (const float*)d_in[iw2];
    const int*   pos    = (const int*)d_in[ip];

    __hip_bfloat16* Hb  = (__hip_bfloat16*)d_ws;
    __hip_bfloat16* Wqb = Hb  + N_HID_ELEM;
    __hip_bfloat16* Wob = Wqb + N_W_ELEM;
    __hip_bfloat16* Q   = Wob + N_W_ELEM;
    __hip_bfloat16* Qr  = Q   + N_HID_ELEM;
    float2*         Tab = reinterpret_cast<float2*>(Qr + N_HID_ELEM);  // 512 KB
    __hip_bfloat16* AO  = Hb;   // Hb dead after gemm1

    int conv4 = (N_HID_ELEM + 2 * N_W_ELEM) / 4;
    int convtot = conv4 + TAB_ELEMS;
    convert_inputs_kernel<<<(convtot + 255) / 256, 256, 0, stream>>>(
        hidden, w1, w2, pos, Hb, Wqb, Wob, Tab);

    dim3 gblk(NROWS / 64, HID_ / 64);   // (64, 12) = 768 blocks

    // GEMM1 + fused RoPE -> Q, Qr
    gemm64ns<1><<<gblk, 256, 0, stream>>>(Hb, Wqb, Q, Qr, nullptr, Tab,
                                          NROWS, HID_, HID_);

    attn_kernel<<<dim3(S_ / 64, B_ * NH_), 256, 0, stream>>>(Q, Qr, AO);

    // GEMM2 -> fp32 out
    gemm64ns<0><<<gblk, 256, 0, stream>>>(AO, Wob, nullptr, nullptr, (float*)d_out,
                                          nullptr, NROWS, HID_, HID_);
}